// Round 2
// baseline (735.947 us; speedup 1.0000x reference)
//
#include <hip/hip_runtime.h>
#include <hip/hip_bf16.h>
#include <math.h>

#define NV 6890
#define NF 13776
#define NVPAD 6912            // 27 * 256
#define NPBLK 27
#define TCH 32                // triangle chunks
#define TPC 431               // ceil(NF / TCH)
#define WN_THRES 0.99
#define EUCL_THRES 0.02f

// ws layout (bytes):
//  [0,4)                      : gm format flag: 0=u8, 1=i32, 2=f32
//  [64, 64+NF*48)             : tris12: per tri 12 floats (A.xyz,0, B.xyz,0, C.xyz,0)
//  [+0, +NV*16)               : x4: (x,y,z,|x|^2) per vertex
//  [+0, +TCH*NVPAD*8)         : partial omega sums (double)
#define WS_TRIS_OFF   64
#define WS_X4_OFF     (64 + NF*48)            // 661312
#define WS_PART_OFF   (64 + NF*48 + NV*16)    // 771552
// total ws use: 771552 + 32*6912*8 = 2,541,024 bytes (~2.5 MB)

__global__ __launch_bounds__(256) void prep_kernel(
    const float* __restrict__ verts, const int* __restrict__ faces,
    const unsigned char* __restrict__ gm_bytes,
    float* __restrict__ tris12, float* __restrict__ x4, int* __restrict__ flag)
{
    int t = blockIdx.x * 256 + threadIdx.x;

    // gather triangle vertices
    if (t < NF) {
        int ia = faces[t*3+0], ib = faces[t*3+1], ic = faces[t*3+2];
        float* o = tris12 + (size_t)t * 12;
        o[0]  = verts[ia*3+0]; o[1]  = verts[ia*3+1]; o[2]  = verts[ia*3+2]; o[3]  = 0.f;
        o[4]  = verts[ib*3+0]; o[5]  = verts[ib*3+1]; o[6]  = verts[ib*3+2]; o[7]  = 0.f;
        o[8]  = verts[ic*3+0]; o[9]  = verts[ic*3+1]; o[10] = verts[ic*3+2]; o[11] = 0.f;
    }
    // packed vertex + squared norm
    if (t < NV) {
        float x = verts[t*3+0], y = verts[t*3+1], z = verts[t*3+2];
        x4[t*4+0] = x; x4[t*4+1] = y; x4[t*4+2] = z;
        x4[t*4+3] = (x*x + y*y) + z*z;   // match jnp sum order
    }
    // geomask dtype detection: first wave of block 0 scans 4096 bytes
    if (blockIdx.x == 0 && threadIdx.x < 64) {
        int lane = threadIdx.x;
        bool any3F = false, anyNZmod = false;
        for (int k = 0; k < 64; ++k) {
            int off = lane * 64 + k;
            unsigned char b = gm_bytes[off];
            if ((off & 3) == 3 && (b == 0x3F || b == 0xBF)) any3F = true;
            if ((off & 3) != 0 && b != 0) anyNZmod = true;
        }
        unsigned long long m3F = __ballot(any3F);
        unsigned long long mNZ = __ballot(anyNZmod);
        if (lane == 0) {
            *flag = m3F ? 2 : (mNZ ? 0 : 1);
        }
    }
}

__global__ __launch_bounds__(256) void wn_kernel(
    const float4* __restrict__ tris12, const float* __restrict__ x4,
    double* __restrict__ partials)
{
    __shared__ float4 shT[TPC * 3];

    int pt = blockIdx.x * 256 + threadIdx.x;   // [0, 6912)
    int tc = blockIdx.y;                       // [0, 32)
    int t0 = tc * TPC;
    int t1 = min(t0 + TPC, NF);
    int nt = t1 - t0;                          // uniform per block

    // stage this chunk's triangles into LDS (coalesced float4)
    for (int k = threadIdx.x; k < nt * 3; k += 256) {
        shT[k] = tris12[(size_t)t0 * 3 + k];
    }
    __syncthreads();

    float px = 0.f, py = 0.f, pz = 0.f;
    if (pt < NV) {
        px = x4[pt*4+0]; py = x4[pt*4+1]; pz = x4[pt*4+2];
    }

    double acc = 0.0;
    for (int k = 0; k < nt; ++k) {
        float4 A = shT[k*3+0];
        float4 B = shT[k*3+1];
        float4 C = shT[k*3+2];
        float ax = A.x - px, ay = A.y - py, az = A.z - pz;
        float bx = B.x - px, by = B.y - py, bz = B.z - pz;
        float cx = C.x - px, cy = C.y - py, cz = C.z - pz;

        float la = sqrtf((ax*ax + ay*ay) + az*az);
        float lb = sqrtf((bx*bx + by*by) + bz*bz);
        float lc = sqrtf((cx*cx + cy*cy) + cz*cz);

        // cross(rb, rc)
        float ux = by*cz - bz*cy;
        float uy = bz*cx - bx*cz;
        float uz = bx*cy - by*cx;
        float det = (ax*ux + ay*uy) + az*uz;

        float dab = (ax*bx + ay*by) + az*bz;
        float dbc = (bx*cx + by*cy) + bz*cz;
        float dca = (cx*ax + cy*ay) + cz*az;

        // left-to-right: la*lb*lc FIRST (keeps +0 for degenerate pairs)
        float denom = la*lb*lc + dab*lc + dbc*la + dca*lb;

        float omega = 2.0f * atan2f(det, denom);
        acc += (double)omega;
    }

    partials[(size_t)tc * NVPAD + pt] = acc;
}

__global__ __launch_bounds__(256) void wn_reduce_kernel(
    const double* __restrict__ partials, float* __restrict__ out_exterior)
{
    int pt = blockIdx.x * 256 + threadIdx.x;
    if (pt >= NV) return;
    double s = 0.0;
    for (int t = 0; t < TCH; ++t) s += partials[(size_t)t * NVPAD + pt];
    double wn = s / 12.566370614359172953850573533118;  // 4*pi
    out_exterior[pt] = (wn <= WN_THRES) ? 1.0f : 0.0f;
}

__global__ __launch_bounds__(256) void v2v_kernel(
    const void* __restrict__ gm, const float4* __restrict__ x4,
    const int* __restrict__ flag_p, float* __restrict__ out)
{
    int j = blockIdx.x;
    int flag = *flag_p;   // uniform scalar

    float4 vj = x4[j];
    float xj = vj.x, yj = vj.y, zj = vj.z, sqj = vj.w;

    float m = INFINITY;
    for (int i = threadIdx.x; i < NV; i += 256) {
        bool g;
        if (flag == 1)      g = ((const int*)gm)[(size_t)j * NV + i] != 0;
        else if (flag == 0) g = ((const unsigned char*)gm)[(size_t)j * NV + i] != 0;
        else                g = ((const float*)gm)[(size_t)j * NV + i] != 0.0f;
        if (g) {
            float4 vi = x4[i];
            float dot = (vi.x*xj + vi.y*yj) + vi.z*zj;
            float d2 = vi.w + sqj - 2.0f * dot;
            m = fminf(m, d2);
        }
    }

    __shared__ float red[256];
    red[threadIdx.x] = m;
    __syncthreads();
    for (int s = 128; s > 0; s >>= 1) {
        if (threadIdx.x < s) red[threadIdx.x] = fminf(red[threadIdx.x], red[threadIdx.x + s]);
        __syncthreads();
    }
    if (threadIdx.x == 0) {
        float d = sqrtf(fmaxf(red[0], 0.f));
        out[j] = d;                                   // v2v_min
        out[NV + j] = (d < EUCL_THRES) ? 1.f : 0.f;   // incontact
    }
}

extern "C" void kernel_launch(void* const* d_in, const int* in_sizes, int n_in,
                              void* d_out, int out_size, void* d_ws, size_t ws_size,
                              hipStream_t stream)
{
    const float* verts = (const float*)d_in[0];
    const int*   faces = (const int*)d_in[1];
    const void*  gm    = d_in[2];
    float* out = (float*)d_out;
    char* ws = (char*)d_ws;

    int*    flag     = (int*)ws;
    float*  tris12   = (float*)(ws + WS_TRIS_OFF);
    float*  x4       = (float*)(ws + WS_X4_OFF);
    double* partials = (double*)(ws + WS_PART_OFF);

    // prep: gather tris, pack verts, detect gm dtype
    int nprep = (NF > NV ? NF : NV);
    prep_kernel<<<(nprep + 255) / 256, 256, 0, stream>>>(
        verts, faces, (const unsigned char*)gm, tris12, x4, flag);

    // winding numbers: 27 point-blocks x 32 triangle-chunks
    wn_kernel<<<dim3(NPBLK, TCH), 256, 0, stream>>>(
        (const float4*)tris12, x4, partials);

    wn_reduce_kernel<<<NPBLK, 256, 0, stream>>>(partials, out + 2 * NV);

    // masked min distance (uses geomask symmetry: read row j, coalesced)
    v2v_kernel<<<NV, 256, 0, stream>>>(gm, (const float4*)x4, flag, out);
}

// Round 3
// 520.886 us; speedup vs baseline: 1.4129x; 1.4129x over previous
//
#include <hip/hip_runtime.h>
#include <hip/hip_bf16.h>
#include <math.h>

#define NV 6890
#define NF 13776
#define NVPAD 6912            // 27 * 256
#define NPBLK 27
#define TCH 64                // triangle chunks
#define TPC 216               // ceil(NF / TCH): 64*216 = 13824 >= 13776
#define WN_THRES 0.99
#define EUCL_THRES 0.02f

// ws layout (bytes) — identical 2.54MB footprint to the round-2 passing version:
//  [0,4)                      : gm format flag: 0=u8, 1=i32, 2=f32
//  [64, 64+NF*48)             : tris12: per tri 12 floats (A.xyz,0, B.xyz,0, C.xyz,0)
//  [+0, +NV*16)               : x4: (x,y,z,|x|^2) per vertex
//  [+0, +TCH*NVPAD*4)         : partial omega sums (float, each a rounded f64 chunk-sum)
#define WS_TRIS_OFF   64
#define WS_X4_OFF     (64 + NF*48)            // 661312
#define WS_PART_OFF   (64 + NF*48 + NV*16)    // 771552
// end: 771552 + 64*6912*4 = 2,541,024 bytes

__global__ __launch_bounds__(256) void prep_kernel(
    const float* __restrict__ verts, const int* __restrict__ faces,
    const unsigned char* __restrict__ gm_bytes,
    float* __restrict__ tris12, float* __restrict__ x4, int* __restrict__ flag)
{
    int t = blockIdx.x * 256 + threadIdx.x;

    if (t < NF) {
        int ia = faces[t*3+0], ib = faces[t*3+1], ic = faces[t*3+2];
        float* o = tris12 + (size_t)t * 12;
        o[0]  = verts[ia*3+0]; o[1]  = verts[ia*3+1]; o[2]  = verts[ia*3+2]; o[3]  = 0.f;
        o[4]  = verts[ib*3+0]; o[5]  = verts[ib*3+1]; o[6]  = verts[ib*3+2]; o[7]  = 0.f;
        o[8]  = verts[ic*3+0]; o[9]  = verts[ic*3+1]; o[10] = verts[ic*3+2]; o[11] = 0.f;
    }
    if (t < NV) {
        float x = verts[t*3+0], y = verts[t*3+1], z = verts[t*3+2];
        x4[t*4+0] = x; x4[t*4+1] = y; x4[t*4+2] = z;
        x4[t*4+3] = (x*x + y*y) + z*z;   // match jnp sum order
    }
    // geomask dtype detection: first wave of block 0 scans 4096 bytes
    if (blockIdx.x == 0 && threadIdx.x < 64) {
        int lane = threadIdx.x;
        bool any3F = false, anyNZmod = false;
        for (int k = 0; k < 64; ++k) {
            int off = lane * 64 + k;
            unsigned char b = gm_bytes[off];
            if ((off & 3) == 3 && (b == 0x3F || b == 0xBF)) any3F = true;
            if ((off & 3) != 0 && b != 0) anyNZmod = true;
        }
        unsigned long long m3F = __ballot(any3F);
        unsigned long long mNZ = __ballot(anyNZmod);
        if (lane == 0) {
            *flag = m3F ? 2 : (mNZ ? 0 : 1);
        }
    }
}

// SLEEF-style atan2: v_rcp instead of IEEE divide, no inf/nan ladder.
// max err ~1e-7 rad on the ranges that occur here.
__device__ __forceinline__ float fast_atan2f(float y, float x)
{
    float ay = __builtin_fabsf(y), ax = __builtin_fabsf(x);
    float mx = fmaxf(ax, ay);
    float mn = fminf(ax, ay);
    float r  = __builtin_amdgcn_rcpf(fmaxf(mx, 1e-37f));   // mx==0 -> t=0 -> p=0
    float t  = mn * r;
    float s  = t * t;
    float u  =              0.00282363896258175373077393f;
    u = fmaf(u, s, -0.0159569028764963150024414f);
    u = fmaf(u, s,  0.0425049886107444763183594f);
    u = fmaf(u, s, -0.0748900920152664184570312f);
    u = fmaf(u, s,  0.106347933411598205566406f);
    u = fmaf(u, s, -0.142027363181114196777344f);
    u = fmaf(u, s,  0.199926957488059997558594f);
    u = fmaf(u, s, -0.333331018686294555664062f);
    float p = fmaf(s * u, t, t);                       // atan(t), t in [0,1]
    p = (ay > ax)  ? (1.5707963267948966f - p) : p;    // |y|>|x| quadrant swap
    p = (x < 0.0f) ? (3.14159265358979323846f - p) : p;
    return copysignf(p, y);
}

__global__ __launch_bounds__(256) void wn_kernel(
    const float4* __restrict__ tris12, const float4* __restrict__ x4,
    float* __restrict__ partials)
{
    int pt = blockIdx.x * 256 + threadIdx.x;   // [0, 6912)
    int tc = blockIdx.y;                       // [0, TCH)
    int t0 = tc * TPC;
    int nt = min(TPC, NF - t0);                // uniform per block

    float4 P = x4[min(pt, NV - 1)];
    float px = P.x, py = P.y, pz = P.z;

    // triangle reads are wave-uniform -> scalar loads (s_load), no LDS needed
    const float4* __restrict__ T = tris12 + (size_t)t0 * 3;

    double acc = 0.0;
    #pragma unroll 2
    for (int k = 0; k < nt; ++k) {
        float4 A = T[3*k+0];
        float4 B = T[3*k+1];
        float4 C = T[3*k+2];
        float ax = A.x - px, ay = A.y - py, az = A.z - pz;
        float bx = B.x - px, by = B.y - py, bz = B.z - pz;
        float cx = C.x - px, cy = C.y - py, cz = C.z - pz;

        float la = __builtin_amdgcn_sqrtf((ax*ax + ay*ay) + az*az);
        float lb = __builtin_amdgcn_sqrtf((bx*bx + by*by) + bz*bz);
        float lc = __builtin_amdgcn_sqrtf((cx*cx + cy*cy) + cz*cz);

        // cross(rb, rc)
        float ux = by*cz - bz*cy;
        float uy = bz*cx - bx*cz;
        float uz = bx*cy - by*cx;
        float det = (ax*ux + ay*uy) + az*uz;

        float dab = (ax*bx + ay*by) + az*bz;
        float dbc = (bx*cx + by*cy) + bz*cz;
        float dca = (cx*ax + cy*ay) + cz*az;

        // left-to-right: la*lb*lc FIRST (keeps +0 for degenerate pairs)
        float denom = la*lb*lc + dab*lc + dbc*la + dca*lb;

        acc += (double)fast_atan2f(det, denom);   // omega = 2*atan2; fold 2x at reduce
    }

    partials[(size_t)tc * NVPAD + pt] = (float)acc;
}

__global__ __launch_bounds__(256) void wn_reduce_kernel(
    const float* __restrict__ partials, float* __restrict__ out_exterior)
{
    int pt = blockIdx.x * 256 + threadIdx.x;
    if (pt >= NV) return;
    double s = 0.0;
    for (int t = 0; t < TCH; ++t) s += (double)partials[(size_t)t * NVPAD + pt];
    double wn = (2.0 * s) / 12.566370614359172953850573533118;  // (2*sum)/(4*pi)
    out_exterior[pt] = (wn <= WN_THRES) ? 1.0f : 0.0f;
}

__device__ __forceinline__ void acc_min(float& m, const float4* __restrict__ x4,
                                        int i, bool g,
                                        float xj, float yj, float zj, float sqj)
{
    float4 vi = x4[i];
    float dot = (vi.x*xj + vi.y*yj) + vi.z*zj;
    float d2  = vi.w + sqj - 2.0f * dot;
    m = fminf(m, g ? d2 : INFINITY);
}

__global__ __launch_bounds__(256) void v2v_kernel(
    const void* __restrict__ gm, const float4* __restrict__ x4,
    const int* __restrict__ flag_p, float* __restrict__ out)
{
    int j = blockIdx.x;
    int tid = threadIdx.x;
    int flag = *flag_p;   // uniform scalar

    float4 vj = x4[j];
    float xj = vj.x, yj = vj.y, zj = vj.z, sqj = vj.w;

    float m = INFINITY;

    if (flag == 0) {
        // u8 path: row stride 6890 (== 2 mod 4) -> lead/tail alignment handling
        const unsigned char* row = (const unsigned char*)gm + (size_t)j * NV;
        int lead = (int)((4u - ((uintptr_t)row & 3u)) & 3u);
        int nw = (NV - lead) >> 2;
        int base = lead + nw * 4;
        int ntail = NV - base;
        if (tid < lead) acc_min(m, x4, tid, row[tid] != 0, xj, yj, zj, sqj);
        const unsigned int* wrow = (const unsigned int*)(row + lead);
        for (int w = tid; w < nw; w += 256) {
            unsigned int v = wrow[w];
            int i0 = lead + w * 4;
            acc_min(m, x4, i0+0, (v & 0x000000FFu) != 0, xj, yj, zj, sqj);
            acc_min(m, x4, i0+1, (v & 0x0000FF00u) != 0, xj, yj, zj, sqj);
            acc_min(m, x4, i0+2, (v & 0x00FF0000u) != 0, xj, yj, zj, sqj);
            acc_min(m, x4, i0+3, (v & 0xFF000000u) != 0, xj, yj, zj, sqj);
        }
        if (tid < ntail) acc_min(m, x4, base + tid, row[base + tid] != 0, xj, yj, zj, sqj);
    } else if (flag == 1) {
        // i32 path: 8B-aligned pairs, NV even -> exactly NV/2 pairs
        const uint2* row = (const uint2*)((const int*)gm + (size_t)j * NV);
        for (int w = tid; w < NV/2; w += 256) {
            uint2 v = row[w];
            int i0 = w * 2;
            acc_min(m, x4, i0+0, v.x != 0, xj, yj, zj, sqj);
            acc_min(m, x4, i0+1, v.y != 0, xj, yj, zj, sqj);
        }
    } else {
        // f32 path
        const float2* row = (const float2*)((const float*)gm + (size_t)j * NV);
        for (int w = tid; w < NV/2; w += 256) {
            float2 v = row[w];
            int i0 = w * 2;
            acc_min(m, x4, i0+0, v.x != 0.0f, xj, yj, zj, sqj);
            acc_min(m, x4, i0+1, v.y != 0.0f, xj, yj, zj, sqj);
        }
    }

    __shared__ float red[256];
    red[tid] = m;
    __syncthreads();
    for (int s = 128; s > 0; s >>= 1) {
        if (tid < s) red[tid] = fminf(red[tid], red[tid + s]);
        __syncthreads();
    }
    if (tid == 0) {
        float d = __builtin_amdgcn_sqrtf(fmaxf(red[0], 0.f));
        out[j] = d;                                   // v2v_min
        out[NV + j] = (d < EUCL_THRES) ? 1.f : 0.f;   // incontact
    }
}

extern "C" void kernel_launch(void* const* d_in, const int* in_sizes, int n_in,
                              void* d_out, int out_size, void* d_ws, size_t ws_size,
                              hipStream_t stream)
{
    const float* verts = (const float*)d_in[0];
    const int*   faces = (const int*)d_in[1];
    const void*  gm    = d_in[2];
    float* out = (float*)d_out;
    char* ws = (char*)d_ws;

    int*   flag     = (int*)ws;
    float* tris12   = (float*)(ws + WS_TRIS_OFF);
    float* x4       = (float*)(ws + WS_X4_OFF);
    float* partials = (float*)(ws + WS_PART_OFF);

    int nprep = (NF > NV ? NF : NV);
    prep_kernel<<<(nprep + 255) / 256, 256, 0, stream>>>(
        verts, faces, (const unsigned char*)gm, tris12, x4, flag);

    // winding numbers: 27 point-blocks x 64 triangle-chunks (1728 blocks, no LDS)
    wn_kernel<<<dim3(NPBLK, TCH), 256, 0, stream>>>(
        (const float4*)tris12, (const float4*)x4, partials);

    wn_reduce_kernel<<<NPBLK, 256, 0, stream>>>(partials, out + 2 * NV);

    // masked min distance (geomask symmetric: read row j, vectorized)
    v2v_kernel<<<NV, 256, 0, stream>>>(gm, (const float4*)x4, flag, out);
}

// Round 4
// 501.852 us; speedup vs baseline: 1.4665x; 1.0379x over previous
//
#include <hip/hip_runtime.h>
#include <math.h>

#define NV 6890
#define NF 13776
#define NVPAD 6912            // 27 * 256
#define NFPAD 13824           // 64 * 216 (zero-padded triangles)
#define NPBLK 27
#define TCH 64                // triangle chunks
#define TPC 216               // NFPAD / TCH, compile-time uniform trip count
#define V2V_BLOCKS 1723       // ceil(NV / 4 rows per block)
#define WN_BLOCKS (NPBLK*TCH) // 1728
#define WN_THRES 0.99
#define EUCL_THRES 0.02f

// ws layout (bytes):
//  [0,4)                       : gm format flag: 0=u8, 1=i32, 2=f32
//  [64, 64+NFPAD*48)           : tris12 (zero-padded past NF)
//  [+0, +NVPAD*16)             : x4: (x,y,z,|x|^2), zero-padded past NV
//  [+0, +TCH*NVPAD*4)          : partial omega sums (f32 chunk sums)
#define WS_TRIS_OFF   64
#define WS_X4_OFF     (64 + NFPAD*48)            // 663616
#define WS_PART_OFF   (WS_X4_OFF + NVPAD*16)     // 774208
// end: 774208 + 64*6912*4 = 2,543,680 bytes (~2.5 MB)

__global__ __launch_bounds__(256) void prep_kernel(
    const float* __restrict__ verts, const int* __restrict__ faces,
    const unsigned char* __restrict__ gm_bytes,
    float* __restrict__ tris12, float* __restrict__ x4, int* __restrict__ flag)
{
    int t = blockIdx.x * 256 + threadIdx.x;

    if (t < NFPAD) {
        float* o = tris12 + (size_t)t * 12;
        if (t < NF) {
            int ia = faces[t*3+0], ib = faces[t*3+1], ic = faces[t*3+2];
            o[0]  = verts[ia*3+0]; o[1]  = verts[ia*3+1]; o[2]  = verts[ia*3+2]; o[3]  = 0.f;
            o[4]  = verts[ib*3+0]; o[5]  = verts[ib*3+1]; o[6]  = verts[ib*3+2]; o[7]  = 0.f;
            o[8]  = verts[ic*3+0]; o[9]  = verts[ic*3+1]; o[10] = verts[ic*3+2]; o[11] = 0.f;
        } else {
            #pragma unroll
            for (int q = 0; q < 12; ++q) o[q] = 0.f;   // degenerate tri -> omega 0
        }
    }
    if (t < NVPAD) {
        if (t < NV) {
            float x = verts[t*3+0], y = verts[t*3+1], z = verts[t*3+2];
            x4[t*4+0] = x; x4[t*4+1] = y; x4[t*4+2] = z;
            x4[t*4+3] = (x*x + y*y) + z*z;   // match jnp sum order
        } else {
            x4[t*4+0] = 0.f; x4[t*4+1] = 0.f; x4[t*4+2] = 0.f; x4[t*4+3] = 0.f;
        }
    }
    // geomask dtype detection: first wave of block 0 scans 4096 bytes
    if (blockIdx.x == 0 && threadIdx.x < 64) {
        int lane = threadIdx.x;
        bool any3F = false, anyNZmod = false;
        for (int k = 0; k < 64; ++k) {
            int off = lane * 64 + k;
            unsigned char b = gm_bytes[off];
            if ((off & 3) == 3 && (b == 0x3F || b == 0xBF)) any3F = true;
            if ((off & 3) != 0 && b != 0) anyNZmod = true;
        }
        unsigned long long m3F = __ballot(any3F);
        unsigned long long mNZ = __ballot(anyNZmod);
        if (lane == 0) {
            *flag = m3F ? 2 : (mNZ ? 0 : 1);
        }
    }
}

// SLEEF-style atan2: v_rcp instead of IEEE divide, no inf/nan ladder.
// The fmaxf(mx,1e-37f) guard is LOAD-BEARING: degenerate pairs (point ==
// triangle vertex) give det=denom=0 and must produce 0, not NaN.
__device__ __forceinline__ float fast_atan2f(float y, float x)
{
    float ay = __builtin_fabsf(y), ax = __builtin_fabsf(x);
    float mx = fmaxf(ax, ay);
    float mn = fminf(ax, ay);
    float r  = __builtin_amdgcn_rcpf(fmaxf(mx, 1e-37f));
    float t  = mn * r;
    float s  = t * t;
    float u  =              0.00282363896258175373077393f;
    u = fmaf(u, s, -0.0159569028764963150024414f);
    u = fmaf(u, s,  0.0425049886107444763183594f);
    u = fmaf(u, s, -0.0748900920152664184570312f);
    u = fmaf(u, s,  0.106347933411598205566406f);
    u = fmaf(u, s, -0.142027363181114196777344f);
    u = fmaf(u, s,  0.199926957488059997558594f);
    u = fmaf(u, s, -0.333331018686294555664062f);
    float p = fmaf(s * u, t, t);                       // atan(t), t in [0,1]
    p = (ay > ax)  ? (1.5707963267948966f - p) : p;
    p = (x < 0.0f) ? (3.14159265358979323846f - p) : p;
    return copysignf(p, y);
}

// Fat kernel: blocks [0, V2V_BLOCKS) do masked-min-distance (memory-heavy),
// blocks [V2V_BLOCKS, V2V_BLOCKS+WN_BLOCKS) do winding numbers (VALU-heavy).
// Co-residency hides v2v's memory traffic under wn's VALU saturation.
__global__ __launch_bounds__(256) void fused_kernel(
    const float4* __restrict__ tris12, const float4* __restrict__ x4,
    float* __restrict__ partials,
    const void* __restrict__ gm, const int* __restrict__ flag_p,
    float* __restrict__ out)
{
    if (blockIdx.x < V2V_BLOCKS) {
        // ---------- v2v: one wave per row j, lane-stride-1 over i ----------
        int w = threadIdx.x >> 6;
        int lane = threadIdx.x & 63;
        int j = blockIdx.x * 4 + w;
        if (j >= NV) return;

        int flag = *flag_p;
        float4 vj = x4[j];
        float m = INFINITY;

#define V2V_BODY(GTEST)                                            \
        {                                                          \
            int i0 = 0;                                            \
            for (; i0 + 64 <= NV; i0 += 64) {                      \
                int i = i0 + lane;                                 \
                bool g = (GTEST);                                  \
                float4 vi = x4[i];                                 \
                float dot = (vi.x*vj.x + vi.y*vj.y) + vi.z*vj.z;   \
                float d2  = vi.w + vj.w - 2.0f*dot;                \
                m = fminf(m, g ? d2 : INFINITY);                   \
            }                                                      \
            int i = i0 + lane;                                     \
            if (i < NV) {                                          \
                bool g = (GTEST);                                  \
                float4 vi = x4[i];                                 \
                float dot = (vi.x*vj.x + vi.y*vj.y) + vi.z*vj.z;   \
                float d2  = vi.w + vj.w - 2.0f*dot;                \
                m = fminf(m, g ? d2 : INFINITY);                   \
            }                                                      \
        }

        if (flag == 0) {
            const unsigned char* row = (const unsigned char*)gm + (size_t)j * NV;
            V2V_BODY(row[i] != 0)
        } else if (flag == 1) {
            const int* row = (const int*)gm + (size_t)j * NV;
            V2V_BODY(row[i] != 0)
        } else {
            const float* row = (const float*)gm + (size_t)j * NV;
            V2V_BODY(row[i] != 0.0f)
        }
#undef V2V_BODY

        #pragma unroll
        for (int k = 32; k > 0; k >>= 1)
            m = fminf(m, __shfl_xor(m, k, 64));
        if (lane == 0) {
            float d = __builtin_amdgcn_sqrtf(fmaxf(m, 0.f));
            out[j] = d;                                   // v2v_min
            out[NV + j] = (d < EUCL_THRES) ? 1.f : 0.f;   // incontact
        }
    } else {
        // ---------- winding numbers ----------
        int wnb = blockIdx.x - V2V_BLOCKS;
        int tc = wnb / NPBLK;                 // 27 consecutive blocks share tc
        int pb = wnb - tc * NPBLK;
        int pt = pb * 256 + threadIdx.x;      // [0, NVPAD), x4 zero-padded

        float4 P = x4[pt];
        float px = P.x, py = P.y, pz = P.z;
        const float4* __restrict__ T = tris12 + (size_t)tc * (TPC * 3);

        double acc = 0.0;
        for (int kk = 0; kk < TPC; kk += 4) {
            float s4 = 0.f;
            #pragma unroll
            for (int u = 0; u < 4; ++u) {
                const float4* Tk = T + 3 * (kk + u);
                float4 A = Tk[0];
                float4 B = Tk[1];
                float4 C = Tk[2];
                float ax = A.x - px, ay = A.y - py, az = A.z - pz;
                float bx = B.x - px, by = B.y - py, bz = B.z - pz;
                float cx = C.x - px, cy = C.y - py, cz = C.z - pz;

                float la = __builtin_amdgcn_sqrtf((ax*ax + ay*ay) + az*az);
                float lb = __builtin_amdgcn_sqrtf((bx*bx + by*by) + bz*bz);
                float lc = __builtin_amdgcn_sqrtf((cx*cx + cy*cy) + cz*cz);

                float ux = by*cz - bz*cy;
                float uy = bz*cx - bx*cz;
                float uz = bx*cy - by*cx;
                float det = (ax*ux + ay*uy) + az*uz;

                float dab = (ax*bx + ay*by) + az*bz;
                float dbc = (bx*cx + by*cy) + bz*cz;
                float dca = (cx*ax + cy*ay) + cz*az;

                // left-to-right: la*lb*lc FIRST (keeps +0 for degenerate pairs)
                float denom = la*lb*lc + dab*lc + dbc*la + dca*lb;

                s4 += fast_atan2f(det, denom);   // omega/2; 2x folded at reduce
            }
            acc += (double)s4;
        }

        partials[(size_t)tc * NVPAD + pt] = (float)acc;
    }
}

__global__ __launch_bounds__(256) void wn_reduce_kernel(
    const float* __restrict__ partials, float* __restrict__ out_exterior)
{
    int pt = blockIdx.x * 256 + threadIdx.x;
    if (pt >= NV) return;
    double s = 0.0;
    for (int t = 0; t < TCH; ++t) s += (double)partials[(size_t)t * NVPAD + pt];
    double wn = (2.0 * s) / 12.566370614359172953850573533118;  // (2*sum)/(4*pi)
    out_exterior[pt] = (wn <= WN_THRES) ? 1.0f : 0.0f;
}

extern "C" void kernel_launch(void* const* d_in, const int* in_sizes, int n_in,
                              void* d_out, int out_size, void* d_ws, size_t ws_size,
                              hipStream_t stream)
{
    const float* verts = (const float*)d_in[0];
    const int*   faces = (const int*)d_in[1];
    const void*  gm    = d_in[2];
    float* out = (float*)d_out;
    char* ws = (char*)d_ws;

    int*   flag     = (int*)ws;
    float* tris12   = (float*)(ws + WS_TRIS_OFF);
    float* x4       = (float*)(ws + WS_X4_OFF);
    float* partials = (float*)(ws + WS_PART_OFF);

    prep_kernel<<<NFPAD / 256, 256, 0, stream>>>(
        verts, faces, (const unsigned char*)gm, tris12, x4, flag);

    fused_kernel<<<V2V_BLOCKS + WN_BLOCKS, 256, 0, stream>>>(
        (const float4*)tris12, (const float4*)x4, partials, gm, flag, out);

    wn_reduce_kernel<<<NPBLK, 256, 0, stream>>>(partials, out + 2 * NV);
}

// Round 5
// 441.389 us; speedup vs baseline: 1.6673x; 1.1370x over previous
//
#include <hip/hip_runtime.h>
#include <math.h>

#define NV 6890
#define NF 13776
#define NVPAD 6912            // 27 * 256
#define NFPAD 13824           // 64 * 216 (zero-padded triangles)
#define HALF 3456             // NVPAD/2: thread handles pt and pt+HALF
#define PBLK 14               // point blocks: 14*256 = 3584 >= HALF
#define TCH 64                // triangle chunks
#define TPC 216               // NFPAD / TCH, compile-time uniform trip count
#define WN_BLOCKS (PBLK*TCH)  // 896
#define V2V_BLOCKS 1723       // ceil(NV / 4 rows per block)
#define RED_BLOCKS 27         // 27*256 covers NV
#define WN_THRES 0.99
#define EUCL_THRES 0.02f

// ws layout (bytes) — same 2.54MB proven footprint:
//  [0,4)                       : gm format flag: 0=u8, 1=i32, 2=f32
//  [64, 64+NFPAD*48)           : tris12 (zero-padded past NF)
//  [+0, +NVPAD*16)             : x4: (x,y,z,|x|^2), zero-padded past NV
//  [+0, +TCH*NVPAD*4)          : partial omega sums (f32 chunk sums)
#define WS_TRIS_OFF   64
#define WS_X4_OFF     (64 + NFPAD*48)            // 663616
#define WS_PART_OFF   (WS_X4_OFF + NVPAD*16)     // 774208
// end: 774208 + 64*6912*4 = 2,543,680 bytes

__global__ __launch_bounds__(256) void prep_kernel(
    const float* __restrict__ verts, const int* __restrict__ faces,
    const unsigned char* __restrict__ gm_bytes,
    float* __restrict__ tris12, float* __restrict__ x4, int* __restrict__ flag)
{
    int t = blockIdx.x * 256 + threadIdx.x;

    if (t < NFPAD) {
        float* o = tris12 + (size_t)t * 12;
        if (t < NF) {
            int ia = faces[t*3+0], ib = faces[t*3+1], ic = faces[t*3+2];
            o[0]  = verts[ia*3+0]; o[1]  = verts[ia*3+1]; o[2]  = verts[ia*3+2]; o[3]  = 0.f;
            o[4]  = verts[ib*3+0]; o[5]  = verts[ib*3+1]; o[6]  = verts[ib*3+2]; o[7]  = 0.f;
            o[8]  = verts[ic*3+0]; o[9]  = verts[ic*3+1]; o[10] = verts[ic*3+2]; o[11] = 0.f;
        } else {
            #pragma unroll
            for (int q = 0; q < 12; ++q) o[q] = 0.f;   // degenerate tri -> omega 0
        }
    }
    if (t < NVPAD) {
        if (t < NV) {
            float x = verts[t*3+0], y = verts[t*3+1], z = verts[t*3+2];
            x4[t*4+0] = x; x4[t*4+1] = y; x4[t*4+2] = z;
            x4[t*4+3] = (x*x + y*y) + z*z;   // match jnp sum order
        } else {
            x4[t*4+0] = 0.f; x4[t*4+1] = 0.f; x4[t*4+2] = 0.f; x4[t*4+3] = 0.f;
        }
    }
    // geomask dtype detection: first wave of block 0 scans 4096 bytes
    if (blockIdx.x == 0 && threadIdx.x < 64) {
        int lane = threadIdx.x;
        bool any3F = false, anyNZmod = false;
        for (int k = 0; k < 64; ++k) {
            int off = lane * 64 + k;
            unsigned char b = gm_bytes[off];
            if ((off & 3) == 3 && (b == 0x3F || b == 0xBF)) any3F = true;
            if ((off & 3) != 0 && b != 0) anyNZmod = true;
        }
        unsigned long long m3F = __ballot(any3F);
        unsigned long long mNZ = __ballot(anyNZmod);
        if (lane == 0) {
            *flag = m3F ? 2 : (mNZ ? 0 : 1);
        }
    }
}

// SLEEF-style atan2: v_rcp instead of IEEE divide, no inf/nan ladder.
// The fmaxf(mx,1e-37f) guard is LOAD-BEARING: degenerate pairs (point ==
// triangle vertex) give det=denom=0 and must produce 0, not NaN.
__device__ __forceinline__ float fast_atan2f(float y, float x)
{
    float ay = __builtin_fabsf(y), ax = __builtin_fabsf(x);
    float mx = fmaxf(ax, ay);
    float mn = fminf(ax, ay);
    float r  = __builtin_amdgcn_rcpf(fmaxf(mx, 1e-37f));
    float t  = mn * r;
    float s  = t * t;
    float u  =              0.00282363896258175373077393f;
    u = fmaf(u, s, -0.0159569028764963150024414f);
    u = fmaf(u, s,  0.0425049886107444763183594f);
    u = fmaf(u, s, -0.0748900920152664184570312f);
    u = fmaf(u, s,  0.106347933411598205566406f);
    u = fmaf(u, s, -0.142027363181114196777344f);
    u = fmaf(u, s,  0.199926957488059997558594f);
    u = fmaf(u, s, -0.333331018686294555664062f);
    float p = fmaf(s * u, t, t);                       // atan(t), t in [0,1]
    p = (ay > ax)  ? (1.5707963267948966f - p) : p;
    p = (x < 0.0f) ? (3.14159265358979323846f - p) : p;
    return copysignf(p, y);
}

// omega/2 for one (point, triangle); bit-identical math to the passing version
#define TRI_OMEGA(A, B, C, PX, PY, PZ, S)                                 \
    {                                                                     \
        float ax = A.x - PX, ay = A.y - PY, az = A.z - PZ;                \
        float bx = B.x - PX, by = B.y - PY, bz = B.z - PZ;                \
        float cx = C.x - PX, cy = C.y - PY, cz = C.z - PZ;                \
        float la = __builtin_amdgcn_sqrtf((ax*ax + ay*ay) + az*az);       \
        float lb = __builtin_amdgcn_sqrtf((bx*bx + by*by) + bz*bz);       \
        float lc = __builtin_amdgcn_sqrtf((cx*cx + cy*cy) + cz*cz);       \
        float ux = by*cz - bz*cy;                                         \
        float uy = bz*cx - bx*cz;                                         \
        float uz = bx*cy - by*cx;                                         \
        float det = (ax*ux + ay*uy) + az*uz;                              \
        float dab = (ax*bx + ay*by) + az*bz;                              \
        float dbc = (bx*cx + by*cy) + bz*cz;                              \
        float dca = (cx*ax + cy*ay) + cz*az;                              \
        float denom = la*lb*lc + dab*lc + dbc*la + dca*lb;                \
        S += fast_atan2f(det, denom);                                     \
    }

// Fat kernel: blocks [0, WN_BLOCKS) = winding numbers (VALU-heavy, critical
// path, launched first); [WN_BLOCKS, WN_BLOCKS+V2V_BLOCKS) = masked min
// distance (memory-heavy, hides under wn VALU saturation).
__global__ __launch_bounds__(256) void fused_kernel(
    const float4* __restrict__ tris12, const float4* __restrict__ x4,
    float* __restrict__ partials,
    const void* __restrict__ gm, const int* __restrict__ flag_p,
    float* __restrict__ out)
{
    if (blockIdx.x < WN_BLOCKS) {
        // ---------- winding numbers: 2 points/thread, ping-pong prefetch ----
        int tc = blockIdx.x / PBLK;           // consecutive blocks share chunk
        int pb = blockIdx.x - tc * PBLK;
        int pt = pb * 256 + threadIdx.x;
        if (pt >= HALF) return;               // no barriers below -> safe exit
        int p1i = pt + HALF;                  // [HALF, NVPAD), x4 zero-padded

        float4 P0 = x4[pt];
        float4 P1 = x4[p1i];
        float px0 = P0.x, py0 = P0.y, pz0 = P0.z;
        float px1 = P1.x, py1 = P1.y, pz1 = P1.z;

        const float4* __restrict__ T = tris12 + (size_t)tc * (TPC * 3);

        float4 A0 = T[0], B0 = T[1], C0 = T[2];
        float4 A1 = T[3], B1 = T[4], C1 = T[5];
        double acc0 = 0.0, acc1 = 0.0;

        for (int kk = 0; kk < TPC; kk += 2) {
            int n0 = 3 * min(kk + 2, TPC - 1);   // guarded prefetch (in-bounds)
            int n1 = 3 * min(kk + 3, TPC - 1);
            float s0 = 0.f, s1 = 0.f;

            TRI_OMEGA(A0, B0, C0, px0, py0, pz0, s0);
            TRI_OMEGA(A0, B0, C0, px1, py1, pz1, s1);
            A0 = T[n0]; B0 = T[n0 + 1]; C0 = T[n0 + 2];

            TRI_OMEGA(A1, B1, C1, px0, py0, pz0, s0);
            TRI_OMEGA(A1, B1, C1, px1, py1, pz1, s1);
            A1 = T[n1]; B1 = T[n1 + 1]; C1 = T[n1 + 2];

            acc0 += (double)s0;
            acc1 += (double)s1;
        }

        partials[(size_t)tc * NVPAD + pt]  = (float)acc0;
        partials[(size_t)tc * NVPAD + p1i] = (float)acc1;
    } else {
        // ---------- v2v: one wave per row j, lane-stride-1 over i ----------
        int bid = blockIdx.x - WN_BLOCKS;
        int w = threadIdx.x >> 6;
        int lane = threadIdx.x & 63;
        int j = bid * 4 + w;
        if (j >= NV) return;

        int flag = *flag_p;
        float4 vj = x4[j];
        float m = INFINITY;

#define V2V_BODY(GTEST)                                            \
        {                                                          \
            int i0 = 0;                                            \
            for (; i0 + 64 <= NV; i0 += 64) {                      \
                int i = i0 + lane;                                 \
                bool g = (GTEST);                                  \
                float4 vi = x4[i];                                 \
                float dot = (vi.x*vj.x + vi.y*vj.y) + vi.z*vj.z;   \
                float d2  = vi.w + vj.w - 2.0f*dot;                \
                m = fminf(m, g ? d2 : INFINITY);                   \
            }                                                      \
            int i = i0 + lane;                                     \
            if (i < NV) {                                          \
                bool g = (GTEST);                                  \
                float4 vi = x4[i];                                 \
                float dot = (vi.x*vj.x + vi.y*vj.y) + vi.z*vj.z;   \
                float d2  = vi.w + vj.w - 2.0f*dot;                \
                m = fminf(m, g ? d2 : INFINITY);                   \
            }                                                      \
        }

        if (flag == 0) {
            const unsigned char* row = (const unsigned char*)gm + (size_t)j * NV;
            V2V_BODY(row[i] != 0)
        } else if (flag == 1) {
            const int* row = (const int*)gm + (size_t)j * NV;
            V2V_BODY(row[i] != 0)
        } else {
            const float* row = (const float*)gm + (size_t)j * NV;
            V2V_BODY(row[i] != 0.0f)
        }
#undef V2V_BODY

        #pragma unroll
        for (int k = 32; k > 0; k >>= 1)
            m = fminf(m, __shfl_xor(m, k, 64));
        if (lane == 0) {
            float d = __builtin_amdgcn_sqrtf(fmaxf(m, 0.f));
            out[j] = d;                                   // v2v_min
            out[NV + j] = (d < EUCL_THRES) ? 1.f : 0.f;   // incontact
        }
    }
}

__global__ __launch_bounds__(256) void wn_reduce_kernel(
    const float* __restrict__ partials, float* __restrict__ out_exterior)
{
    int pt = blockIdx.x * 256 + threadIdx.x;
    if (pt >= NV) return;
    double s = 0.0;
    for (int t = 0; t < TCH; ++t) s += (double)partials[(size_t)t * NVPAD + pt];
    double wn = (2.0 * s) / 12.566370614359172953850573533118;  // (2*sum)/(4*pi)
    out_exterior[pt] = (wn <= WN_THRES) ? 1.0f : 0.0f;
}

extern "C" void kernel_launch(void* const* d_in, const int* in_sizes, int n_in,
                              void* d_out, int out_size, void* d_ws, size_t ws_size,
                              hipStream_t stream)
{
    const float* verts = (const float*)d_in[0];
    const int*   faces = (const int*)d_in[1];
    const void*  gm    = d_in[2];
    float* out = (float*)d_out;
    char* ws = (char*)d_ws;

    int*   flag     = (int*)ws;
    float* tris12   = (float*)(ws + WS_TRIS_OFF);
    float* x4       = (float*)(ws + WS_X4_OFF);
    float* partials = (float*)(ws + WS_PART_OFF);

    prep_kernel<<<NFPAD / 256, 256, 0, stream>>>(
        verts, faces, (const unsigned char*)gm, tris12, x4, flag);

    fused_kernel<<<WN_BLOCKS + V2V_BLOCKS, 256, 0, stream>>>(
        (const float4*)tris12, (const float4*)x4, partials, gm, flag, out);

    wn_reduce_kernel<<<RED_BLOCKS, 256, 0, stream>>>(partials, out + 2 * NV);
}